// Round 15
// baseline (407.861 us; speedup 1.0000x reference)
//
#include <hip/hip_runtime.h>
#include <hip/hip_bf16.h>
#include <hip/hip_fp16.h>

typedef __hip_bfloat16 bf16;
typedef short s16x8 __attribute__((ext_vector_type(8)));
typedef float f32x4 __attribute__((ext_vector_type(4)));
typedef int   i32x4 __attribute__((ext_vector_type(4)));

// B=4 N=2048 E=512 H=8 K=128 D=192, D1=1536, tokens=8192, FFT length 8192

static __device__ __forceinline__ float silu_f(float v){
  return v / (1.f + __expf(-v));
}

// async global->LDS, 16B per lane; dest must be wave-uniform base + lane*16 (ours is)
#define GLDS16(g, l) __builtin_amdgcn_global_load_lds( \
    (const __attribute__((address_space(1))) void*)(g), \
    (__attribute__((address_space(3))) void*)(l), 16, 0, 0)

// ---------------- fused prep: all dtype converts/splits in one launch ----------------
__global__ void prep_kernel(const float* __restrict__ x,  const float* __restrict__ Wu,
                            const float* __restrict__ Wv, const float* __restrict__ Wo,
                            const float* __restrict__ coef, const float* __restrict__ vander,
                            bf16* __restrict__ xb, bf16* __restrict__ wuv_hi, bf16* __restrict__ wuv_lo,
                            bf16* __restrict__ wo_b, bf16* __restrict__ ct_hi, bf16* __restrict__ ct_lo,
                            bf16* __restrict__ vb_hi, bf16* __restrict__ vb_lo){
  long i = (long)blockIdx.x * 256 + threadIdx.x;
  if (i < 4194304){ xb[i] = __float2bfloat16(x[i]); return; }
  i -= 4194304;
  if (i < 786432){
    float v = Wu[i]; bf16 h = __float2bfloat16(v);
    wuv_hi[i] = h; wuv_lo[i] = __float2bfloat16(v - __bfloat162float(h)); return;
  }
  i -= 786432;
  if (i < 786432){
    float v = Wv[i]; bf16 h = __float2bfloat16(v);
    wuv_hi[786432 + i] = h; wuv_lo[786432 + i] = __float2bfloat16(v - __bfloat162float(h)); return;
  }
  i -= 786432;
  if (i < 786432){ wo_b[i] = __float2bfloat16(Wo[i]); return; }
  i -= 786432;
  if (i < 196608){
    int hd = (int)(i >> 7), k = (int)(i & 127);
    int h = hd / 192, dd = hd - h * 192;
    float v = coef[(h * 128 + k) * 192 + dd];
    bf16 hb = __float2bfloat16(v);
    ct_hi[i] = hb; ct_lo[i] = __float2bfloat16(v - __bfloat162float(hb)); return;
  }
  i -= 196608;
  if (i < 524288){
    float v = (i >> 7) < 4095 ? vander[i] : 0.f;
    bf16 hb = __float2bfloat16(v);
    vb_hi[i] = hb; vb_lo[i] = __float2bfloat16(v - __bfloat162float(hb));
  }
}

// ---------------- GEMM: merged split-precision phases (r14, WIN) ----------------
__global__ __launch_bounds__(256)
void gemm_bf16(const bf16* __restrict__ A, const bf16* __restrict__ Alo,
               const bf16* __restrict__ Bt, const bf16* __restrict__ Btlo,
               int K, int N, int useAlo, int useBlo, int mode,
               const float* __restrict__ bias0, const float* __restrict__ bias1,
               void* __restrict__ out0, void* __restrict__ out1)
{
  __shared__ bf16 As [128 * 32];
  __shared__ bf16 Als[128 * 32];
  __shared__ bf16 Bs [128 * 32];
  __shared__ bf16 Bls[128 * 32];
  const int tid  = threadIdx.x;
  const int lane = tid & 63;
  const int wave = tid >> 6;
  const int wr = wave >> 1, wc = wave & 1;
  const int bm = blockIdx.y * 128;
  const int bn = blockIdx.x * 128;

  const int c0i = tid, c1i = tid + 256;
  const int rA0 = c0i >> 2, cA0 = (c0i & 3) << 3;
  const int rA1 = c1i >> 2, cA1 = (c1i & 3) << 3;

  const bf16* Ab  = A  + (size_t)bm * K;
  const bf16* Alb = useAlo ? (Alo  + (size_t)bm * K) : nullptr;
  const bf16* Bb  = Bt + (size_t)bn * K;
  const bf16* Blb = useBlo ? (Btlo + (size_t)bn * K) : nullptr;

  f32x4 acc[4][4];
#pragma unroll
  for (int i = 0; i < 4; i++)
#pragma unroll
    for (int j = 0; j < 4; j++) acc[i][j] = (f32x4){0.f, 0.f, 0.f, 0.f};

  const int laneRow = lane & 15;
  const int laneK   = (lane >> 4) << 3;

  for (int k0 = 0; k0 < K; k0 += 32){
    __syncthreads();
    GLDS16(Ab + (size_t)rA0 * K + k0 + cA0, As + c0i * 8);
    GLDS16(Ab + (size_t)rA1 * K + k0 + cA1, As + c1i * 8);
    GLDS16(Bb + (size_t)rA0 * K + k0 + cA0, Bs + c0i * 8);
    GLDS16(Bb + (size_t)rA1 * K + k0 + cA1, Bs + c1i * 8);
    if (useBlo){
      GLDS16(Blb + (size_t)rA0 * K + k0 + cA0, Bls + c0i * 8);
      GLDS16(Blb + (size_t)rA1 * K + k0 + cA1, Bls + c1i * 8);
    }
    if (useAlo){
      GLDS16(Alb + (size_t)rA0 * K + k0 + cA0, Als + c0i * 8);
      GLDS16(Alb + (size_t)rA1 * K + k0 + cA1, Als + c1i * 8);
    }
    __syncthreads();
    s16x8 af[4], bv[4];
#pragma unroll
    for (int mi = 0; mi < 4; mi++)
      af[mi] = *(const s16x8*)(As + (wr * 64 + mi * 16 + laneRow) * 32 + laneK);
#pragma unroll
    for (int ni = 0; ni < 4; ni++)
      bv[ni] = *(const s16x8*)(Bs + (wc * 64 + ni * 16 + laneRow) * 32 + laneK);
#pragma unroll
    for (int mi = 0; mi < 4; mi++)
#pragma unroll
      for (int ni = 0; ni < 4; ni++)
        acc[mi][ni] = __builtin_amdgcn_mfma_f32_16x16x32_bf16(af[mi], bv[ni], acc[mi][ni], 0, 0, 0);
    if (useBlo){
      s16x8 bl[4];
#pragma unroll
      for (int ni = 0; ni < 4; ni++)
        bl[ni] = *(const s16x8*)(Bls + (wc * 64 + ni * 16 + laneRow) * 32 + laneK);
#pragma unroll
      for (int mi = 0; mi < 4; mi++)
#pragma unroll
        for (int ni = 0; ni < 4; ni++)
          acc[mi][ni] = __builtin_amdgcn_mfma_f32_16x16x32_bf16(af[mi], bl[ni], acc[mi][ni], 0, 0, 0);
    }
    if (useAlo){
      s16x8 al[4];
#pragma unroll
      for (int mi = 0; mi < 4; mi++)
        al[mi] = *(const s16x8*)(Als + (wr * 64 + mi * 16 + laneRow) * 32 + laneK);
#pragma unroll
      for (int mi = 0; mi < 4; mi++)
#pragma unroll
        for (int ni = 0; ni < 4; ni++)
          acc[mi][ni] = __builtin_amdgcn_mfma_f32_16x16x32_bf16(al[mi], bv[ni], acc[mi][ni], 0, 0, 0);
    }
  }

  const int rowOff = (lane >> 4) << 2;
#pragma unroll
  for (int mi = 0; mi < 4; mi++){
    const int rowb = bm + wr * 64 + mi * 16 + rowOff;
#pragma unroll
    for (int ni = 0; ni < 4; ni++){
      const int col = bn + wc * 64 + ni * 16 + laneRow;
#pragma unroll
      for (int r = 0; r < 4; r++){
        const int row = rowb + r;
        float val = acc[mi][ni][r];
        if (mode == 0){
          float bsv = (col < 1536) ? bias0[col] : bias1[col - 1536];
          val = silu_f(val + bsv);
          if (col < 1536) ((bf16*)out0)[(size_t)row * 1536 + col] = __float2bfloat16(val);
          else            ((bf16*)out1)[(size_t)row * 1536 + (col - 1536)] = __float2bfloat16(val);
        } else if (mode == 1){
          ((float*)out0)[(size_t)row * N + col] = val;
        } else {
          ((float*)out0)[(size_t)row * N + col] = val + bias0[col];
        }
      }
    }
  }
}

// ---------------- transpose / gate (unchanged) ----------------
__global__ void transpose_v_kernel(const bf16* __restrict__ v_nat, bf16* __restrict__ v_t){
  __shared__ bf16 tile[32][33];
  const int tx = threadIdx.x & 31, ty = threadIdx.x >> 5;
  const int c0 = blockIdx.x * 32;
  const int r0 = blockIdx.y * 32;
  const int b  = r0 >> 11;
  const int i0 = r0 & 2047;
#pragma unroll
  for (int yy = ty; yy < 32; yy += 8)
    tile[yy][tx] = v_nat[(size_t)(r0 + yy) * 1536 + c0 + tx];
  __syncthreads();
#pragma unroll
  for (int yy = ty; yy < 32; yy += 8)
    v_t[((size_t)b * 1536 + c0 + yy) * 2048 + i0 + tx] = tile[tx][yy];
}

__global__ void gate_kernel(const bf16* __restrict__ u_bf, const bf16* __restrict__ conv_t,
                            bf16* __restrict__ gateA){
  __shared__ bf16 tile[32][33];
  const int tx = threadIdx.x & 31, ty = threadIdx.x >> 5;
  const int c0 = blockIdx.x * 32;
  const int r0 = blockIdx.y * 32;
  const int b  = r0 >> 11;
  const int i0 = r0 & 2047;
#pragma unroll
  for (int yy = ty; yy < 32; yy += 8)
    tile[yy][tx] = conv_t[((size_t)b * 1536 + c0 + yy) * 2048 + i0 + tx];
  __syncthreads();
#pragma unroll
  for (int yy = ty; yy < 32; yy += 8){
    const size_t idx = (size_t)(r0 + yy) * 1536 + c0 + tx;
    float g = __bfloat162float(u_bf[idx]) * __bfloat162float(tile[tx][yy]);
    gateA[idx] = __float2bfloat16(g);
  }
}

// ---------------- FFT conv: half2-packed LDS (one dword per complex) ----------------
// r14 counters: conv latency-bound, 1 block/CU (LDS 139.8KB). f16 packing:
// cS 36.9KB + Tsp 33KB = 69.9KB <= 80KB -> HW fits 2 blocks/CU at VGPR=128
// (m69: 4 waves/EU at 128). LDS instr count also halves (one b32 per complex).
// Precision: ~6 f16 quantizations @2^-11 rel -> absmax ~0.012-0.02 (budget 0.0345).

#define R2C 0.70710678118654752f

__device__ __forceinline__ int phys(int i){ return i + (i >> 3); }

__device__ __forceinline__ unsigned int packh2(float a, float b){
  __half2 h = __floats2half2_rn(a, b);
  return *(unsigned int*)&h;
}
__device__ __forceinline__ float2 unpackh2(unsigned int w){
  __half2 h = *(__half2*)&w;
  return __half22float2(h);
}

#define SINCOS_REV(rev, sn_, cs_) { const float _rv = (rev); \
  sn_ = __builtin_amdgcn_sinf(_rv); cs_ = __builtin_amdgcn_cosf(_rv); }

#define BFF(xr,xi,yr,yi,tr_,ti_) { float sr_=(xr)-(yr), si_=(xi)-(yi); (xr)+=(yr); (xi)+=(yi); (yr)=sr_*(tr_)-si_*(ti_); (yi)=sr_*(ti_)+si_*(tr_); }
#define BFI(xr,xi,yr,yi,tr_,ti_) { float pr_=(yr)*(tr_)-(yi)*(ti_), pi_=(yr)*(ti_)+(yi)*(tr_); (yr)=(xr)-pr_; (yi)=(xi)-pi_; (xr)+=pr_; (xi)+=pi_; }

__device__ __forceinline__ void fwd_reg(float* r, float* m, int t){
  float sn, cs;
#pragma unroll
  for (int a = 0; a < 8; a++){
    SINCOS_REV(-(float)(t + 512*a) * (1.f/8192.f), sn, cs);
    BFF(r[a],m[a], r[a+8],m[a+8], cs, sn);
  }
#pragma unroll
  for (int a = 0; a < 4; a++){
    SINCOS_REV(-(float)(t + 512*a) * (1.f/4096.f), sn, cs);
    BFF(r[a],m[a], r[a+4],m[a+4], cs, sn);
    BFF(r[a+8],m[a+8], r[a+12],m[a+12], cs, sn);
  }
#pragma unroll
  for (int a = 0; a < 2; a++){
    SINCOS_REV(-(float)(t + 512*a) * (1.f/2048.f), sn, cs);
    BFF(r[a],m[a], r[a+2],m[a+2], cs, sn);
    BFF(r[a+4],m[a+4], r[a+6],m[a+6], cs, sn);
    BFF(r[a+8],m[a+8], r[a+10],m[a+10], cs, sn);
    BFF(r[a+12],m[a+12], r[a+14],m[a+14], cs, sn);
  }
  SINCOS_REV(-(float)t * (1.f/1024.f), sn, cs);
#pragma unroll
  for (int e = 0; e < 8; e++){
    BFF(r[2*e],m[2*e], r[2*e+1],m[2*e+1], cs, sn);
  }
}

__device__ __forceinline__ void inv_reg(float* r, float* m, int t){
  float sn, cs;
  SINCOS_REV((float)t * (1.f/1024.f), sn, cs);
#pragma unroll
  for (int e = 0; e < 8; e++){
    BFI(r[2*e],m[2*e], r[2*e+1],m[2*e+1], cs, sn);
  }
#pragma unroll
  for (int a = 0; a < 2; a++){
    SINCOS_REV((float)(t + 512*a) * (1.f/2048.f), sn, cs);
    BFI(r[a],m[a], r[a+2],m[a+2], cs, sn);
    BFI(r[a+4],m[a+4], r[a+6],m[a+6], cs, sn);
    BFI(r[a+8],m[a+8], r[a+10],m[a+10], cs, sn);
    BFI(r[a+12],m[a+12], r[a+14],m[a+14], cs, sn);
  }
#pragma unroll
  for (int a = 0; a < 4; a++){
    SINCOS_REV((float)(t + 512*a) * (1.f/4096.f), sn, cs);
    BFI(r[a],m[a], r[a+4],m[a+4], cs, sn);
    BFI(r[a+8],m[a+8], r[a+12],m[a+12], cs, sn);
  }
#pragma unroll
  for (int a = 0; a < 8; a++){
    SINCOS_REV((float)(t + 512*a) * (1.f/8192.f), sn, cs);
    BFI(r[a],m[a], r[a+8],m[a+8], cs, sn);
  }
}

__device__ __forceinline__ void lds_stage_fwd(unsigned int* cS, int t, int stride){
  const int pos = (stride == 64) ? (t & 63) : (t & 7);
  float ui, ur;
  SINCOS_REV(-(float)pos / (float)(stride * 8), ui, ur);
  const float u2r = ur*ur - ui*ui, u2i = 2.f*ur*ui;
  const float u4r = u2r*u2r - u2i*u2i, u4i = 2.f*u2r*u2i;
  const float t1r[4] = { ur, R2C*(ur+ui), ui, R2C*(ui-ur) };
  const float t1i[4] = { ui, R2C*(ui-ur), -ur, -R2C*(ur+ui) };
  const float t2r[2] = { u2r, u2i };
  const float t2i[2] = { u2i, -u2r };
#pragma unroll
  for (int rep = 0; rep < 2; rep++){
    const int tau = t + rep*512;
    const int base = (stride == 64) ? (((tau >> 6) << 9) + (tau & 63))
                                    : (((tau >> 3) << 6) + (tau & 7));
    float zr[8], zi[8];
#pragma unroll
    for (int q = 0; q < 8; q++){ float2 z = unpackh2(cS[phys(base + stride*q)]); zr[q] = z.x; zi[q] = z.y; }
#pragma unroll
    for (int q = 0; q < 4; q++){ BFF(zr[q],zi[q], zr[q+4],zi[q+4], t1r[q], t1i[q]); }
    BFF(zr[0],zi[0], zr[2],zi[2], t2r[0], t2i[0]);
    BFF(zr[1],zi[1], zr[3],zi[3], t2r[1], t2i[1]);
    BFF(zr[4],zi[4], zr[6],zi[6], t2r[0], t2i[0]);
    BFF(zr[5],zi[5], zr[7],zi[7], t2r[1], t2i[1]);
    BFF(zr[0],zi[0], zr[1],zi[1], u4r, u4i);
    BFF(zr[2],zi[2], zr[3],zi[3], u4r, u4i);
    BFF(zr[4],zi[4], zr[5],zi[5], u4r, u4i);
    BFF(zr[6],zi[6], zr[7],zi[7], u4r, u4i);
#pragma unroll
    for (int q = 0; q < 8; q++){ cS[phys(base + stride*q)] = packh2(zr[q], zi[q]); }
  }
}

__device__ __forceinline__ void lds_stage_inv(unsigned int* cS, int t, int stride){
  const int pos = (stride == 64) ? (t & 63) : (t & 7);
  float ui, ur;
  SINCOS_REV((float)pos / (float)(stride * 8), ui, ur);
  const float u2r = ur*ur - ui*ui, u2i = 2.f*ur*ui;
  const float u4r = u2r*u2r - u2i*u2i, u4i = 2.f*u2r*u2i;
  const float t1r[4] = { ur, R2C*(ur-ui), -ui, -R2C*(ur+ui) };
  const float t1i[4] = { ui, R2C*(ur+ui), ur, R2C*(ur-ui) };
  const float t2r[2] = { u2r, -u2i };
  const float t2i[2] = { u2i, u2r };
#pragma unroll
  for (int rep = 0; rep < 2; rep++){
    const int tau = t + rep*512;
    const int base = (stride == 64) ? (((tau >> 6) << 9) + (tau & 63))
                                    : (((tau >> 3) << 6) + (tau & 7));
    float zr[8], zi[8];
#pragma unroll
    for (int q = 0; q < 8; q++){ float2 z = unpackh2(cS[phys(base + stride*q)]); zr[q] = z.x; zi[q] = z.y; }
    BFI(zr[0],zi[0], zr[1],zi[1], u4r, u4i);
    BFI(zr[2],zi[2], zr[3],zi[3], u4r, u4i);
    BFI(zr[4],zi[4], zr[5],zi[5], u4r, u4i);
    BFI(zr[6],zi[6], zr[7],zi[7], u4r, u4i);
    BFI(zr[0],zi[0], zr[2],zi[2], t2r[0], t2i[0]);
    BFI(zr[1],zi[1], zr[3],zi[3], t2r[1], t2i[1]);
    BFI(zr[4],zi[4], zr[6],zi[6], t2r[0], t2i[0]);
    BFI(zr[5],zi[5], zr[7],zi[7], t2r[1], t2i[1]);
#pragma unroll
    for (int q = 0; q < 4; q++){ BFI(zr[q],zi[q], zr[q+4],zi[q+4], t1r[q], t1i[q]); }
#pragma unroll
    for (int q = 0; q < 8; q++){ cS[phys(base + stride*q)] = packh2(zr[q], zi[q]); }
  }
}

__device__ __forceinline__ void octet_fwd_c(float* zr, float* zi){
  BFF(zr[0],zi[0], zr[4],zi[4], 1.f, 0.f);
  BFF(zr[1],zi[1], zr[5],zi[5], R2C, -R2C);
  BFF(zr[2],zi[2], zr[6],zi[6], 0.f, -1.f);
  BFF(zr[3],zi[3], zr[7],zi[7], -R2C, -R2C);
  BFF(zr[0],zi[0], zr[2],zi[2], 1.f, 0.f);
  BFF(zr[1],zi[1], zr[3],zi[3], 0.f, -1.f);
  BFF(zr[4],zi[4], zr[6],zi[6], 1.f, 0.f);
  BFF(zr[5],zi[5], zr[7],zi[7], 0.f, -1.f);
  BFF(zr[0],zi[0], zr[1],zi[1], 1.f, 0.f);
  BFF(zr[2],zi[2], zr[3],zi[3], 1.f, 0.f);
  BFF(zr[4],zi[4], zr[5],zi[5], 1.f, 0.f);
  BFF(zr[6],zi[6], zr[7],zi[7], 1.f, 0.f);
}

__device__ __forceinline__ void octet_inv_c(float* zr, float* zi){
  BFI(zr[0],zi[0], zr[1],zi[1], 1.f, 0.f);
  BFI(zr[2],zi[2], zr[3],zi[3], 1.f, 0.f);
  BFI(zr[4],zi[4], zr[5],zi[5], 1.f, 0.f);
  BFI(zr[6],zi[6], zr[7],zi[7], 1.f, 0.f);
  BFI(zr[0],zi[0], zr[2],zi[2], 1.f, 0.f);
  BFI(zr[1],zi[1], zr[3],zi[3], 0.f, 1.f);
  BFI(zr[4],zi[4], zr[6],zi[6], 1.f, 0.f);
  BFI(zr[5],zi[5], zr[7],zi[7], 0.f, 1.f);
  BFI(zr[0],zi[0], zr[4],zi[4], 1.f, 0.f);
  BFI(zr[1],zi[1], zr[5],zi[5], R2C, R2C);
  BFI(zr[2],zi[2], zr[6],zi[6], 0.f, 1.f);
  BFI(zr[3],zi[3], zr[7],zi[7], -R2C, R2C);
}

__global__ __launch_bounds__(512, 1)
void conv_fft_kernel(const float* __restrict__ t_time, const bf16* __restrict__ v_t,
                     bf16* __restrict__ conv_t){
  __shared__ unsigned int cS[9216];      // half2(re,im) per complex; 36.9 KB
  __shared__ unsigned int TspU[16*516];  // filter spectrum, half2, thread-private cols; 33 KB
  const int t  = threadIdx.x;
  const int hd = blockIdx.x;
  float r[16], m[16];

  // ---- filter forward FFT (fp32 regs, f16 thru LDS) ----
  const float* trow = t_time + (size_t)hd * 4096;
#pragma unroll
  for (int a = 0; a < 16; a++){
    r[a] = (a < 8) ? trow[t + 512*a] : 0.f;
    m[a] = 0.f;
  }
  fwd_reg(r, m, t);
#pragma unroll
  for (int a = 0; a < 16; a++){ cS[phys(t + 512*a)] = packh2(r[a], m[a]); }
  __syncthreads();
  lds_stage_fwd(cS, t, 64);
  __syncthreads();
  lds_stage_fwd(cS, t, 8);
  __syncthreads();
#pragma unroll
  for (int o = 0; o < 2; o++){
    const int b8 = (t + 512*o) * 8;
    float zr[8], zi[8];
#pragma unroll
    for (int e = 0; e < 8; e++){ float2 z = unpackh2(cS[phys(b8 + e)]); zr[e] = z.x; zi[e] = z.y; }
    octet_fwd_c(zr, zi);
#pragma unroll
    for (int e = 0; e < 8; e++){
      TspU[(8*o + e) * 516 + t] = packh2(zr[e], zi[e]);
    }
  }

  // ---- batches, packed two per complex FFT (filter is real) ----
  for (int pair = 0; pair < 2; pair++){
    const bf16* v0 = v_t + ((size_t)(2*pair)     * 1536 + hd) * 2048;
    const bf16* v1 = v_t + ((size_t)(2*pair + 1) * 1536 + hd) * 2048;
#pragma unroll
    for (int a = 0; a < 16; a++){
      if (a < 4){ int idx = t + 512*a; r[a] = __bfloat162float(v0[idx]); m[a] = __bfloat162float(v1[idx]); }
      else      { r[a] = 0.f; m[a] = 0.f; }
    }
    fwd_reg(r, m, t);
    __syncthreads();   // prior LDS reads (filter octets / prev pair comb) complete
#pragma unroll
    for (int a = 0; a < 16; a++){ cS[phys(t + 512*a)] = packh2(r[a], m[a]); }
    __syncthreads();
    lds_stage_fwd(cS, t, 64);
    __syncthreads();
    lds_stage_fwd(cS, t, 8);
    __syncthreads();
    // fused: forward h=4,2,1 + pointwise product (T from TspU) + inverse h=1,2,4
#pragma unroll
    for (int o = 0; o < 2; o++){
      const int b8 = (t + 512*o) * 8;
      float zr[8], zi[8];
#pragma unroll
      for (int e = 0; e < 8; e++){ float2 z = unpackh2(cS[phys(b8 + e)]); zr[e] = z.x; zi[e] = z.y; }
      octet_fwd_c(zr, zi);
#pragma unroll
      for (int e = 0; e < 8; e++){
        float2 tw = unpackh2(TspU[(8*o + e) * 516 + t]);
        const float ar = zr[e], ai = zi[e];
        zr[e] = ar*tw.x - ai*tw.y;
        zi[e] = ar*tw.y + ai*tw.x;
      }
      octet_inv_c(zr, zi);
#pragma unroll
      for (int e = 0; e < 8; e++){ cS[phys(b8 + e)] = packh2(zr[e], zi[e]); }
    }
    __syncthreads();
    lds_stage_inv(cS, t, 8);
    __syncthreads();
    lds_stage_inv(cS, t, 64);
    __syncthreads();
#pragma unroll
    for (int a = 0; a < 16; a++){ float2 z = unpackh2(cS[phys(t + 512*a)]); r[a] = z.x; m[a] = z.y; }
    inv_reg(r, m, t);
    // window tau = 2047..4094 -> exact linear conv outputs 0..2047 (no wrap at L=8192)
    bf16* c0 = conv_t + ((size_t)(2*pair)     * 1536 + hd) * 2048;
    bf16* c1 = conv_t + ((size_t)(2*pair + 1) * 1536 + hd) * 2048;
    const float s = 1.f / 8192.f;
#pragma unroll
    for (int a = 0; a < 16; a++){
      const int j = t + 512*a - 2047;
      if (j >= 0 && j < 2048){
        c0[j] = __float2bfloat16(r[a] * s);
        c1[j] = __float2bfloat16(m[a] * s);
      }
    }
  }
}

extern "C" void kernel_launch(void* const* d_in, const int* in_sizes, int n_in,
                              void* d_out, int out_size, void* d_ws, size_t ws_size,
                              hipStream_t stream)
{
  (void)in_sizes; (void)n_in; (void)out_size; (void)ws_size;
  const float* x      = (const float*)d_in[0];
  const float* vander = (const float*)d_in[1];
  // d_in[2] = index (Toeplitz gather indices) — unused
  const float* coef   = (const float*)d_in[3];
  const float* Wu     = (const float*)d_in[4];
  const float* bu     = (const float*)d_in[5];
  const float* Wv     = (const float*)d_in[6];
  const float* bv     = (const float*)d_in[7];
  const float* Wo     = (const float*)d_in[8];
  const float* bo     = (const float*)d_in[9];

  char* ws = (char*)d_ws;
  size_t off = 0;
  auto alloc = [&](size_t bytes) -> void* { void* p = ws + off; off += bytes; return p; };

  bf16*  xb     = (bf16*) alloc((size_t)8192 * 512 * 2);    // x bf16
  bf16*  wuv_hi = (bf16*) alloc((size_t)3072 * 512 * 2);
  bf16*  wuv_lo = (bf16*) alloc((size_t)3072 * 512 * 2);
  bf16*  wo_b   = (bf16*) alloc((size_t)512 * 1536 * 2);
  bf16*  ct_hi  = (bf16*) alloc((size_t)1536 * 128 * 2);
  bf16*  ct_lo  = (bf16*) alloc((size_t)1536 * 128 * 2);
  bf16*  vb_hi  = (bf16*) alloc((size_t)4096 * 128 * 2);
  bf16*  vb_lo  = (bf16*) alloc((size_t)4096 * 128 * 2);
  bf16*  u_bf   = (bf16*) alloc((size_t)8192 * 1536 * 2);
  bf16*  v_bf   = (bf16*) alloc((size_t)8192 * 1536 * 2);   // (token, hd); reused as conv_t
  bf16*  v_t    = (bf16*) alloc((size_t)8192 * 1536 * 2);   // (b, hd, i)
  float* t_time = (float*)alloc((size_t)1536 * 4096 * 4);   // reused as gateA

  bf16* conv_t = v_bf;            // v_bf dead after transpose
  bf16* gateA  = (bf16*)t_time;   // t_time dead after conv kernel

  // all converts in one launch (7,274,496 items)
  prep_kernel<<<28416, 256, 0, stream>>>(x, Wu, Wv, Wo, coef, vander,
                                         xb, wuv_hi, wuv_lo, wo_b, ct_hi, ct_lo, vb_hi, vb_lo);

  // G1 (merged bf16x2): [u|v] = silu(x @ [Wu;Wv]^T + b)
  gemm_bf16<<<dim3(24, 64), 256, 0, stream>>>(xb, nullptr, wuv_hi, wuv_lo,
                                              512, 3072, 0, 1, 0, bu, bv, u_bf, v_bf);
  transpose_v_kernel<<<dim3(48, 256), 256, 0, stream>>>(v_bf, v_t);
  // G2 (merged bf16x3): t = ct_hi*vb_hi + ct_hi*vb_lo + ct_lo*vb_hi
  gemm_bf16<<<dim3(32, 12), 256, 0, stream>>>(ct_hi, ct_lo, vb_hi, vb_lo,
                                              128, 4096, 1, 1, 1, nullptr, nullptr, t_time, nullptr);
  // FFT convolution per hd channel (half2 LDS -> 2 blocks/CU)
  conv_fft_kernel<<<1536, 512, 0, stream>>>(t_time, v_t, conv_t);
  // gate: A = u * conv
  gate_kernel<<<dim3(48, 256), 256, 0, stream>>>(u_bf, conv_t, gateA);
  // G3: out = A @ Wo^T + bo  (8192 x 512, K=1536), fp32 store to d_out
  gemm_bf16<<<dim3(4, 64), 256, 0, stream>>>(gateA, gateA, wo_b, wo_b,
                                             1536, 512, 0, 0, 2, bo, nullptr, d_out, nullptr);
}

// Round 16
// 338.643 us; speedup vs baseline: 1.2044x; 1.2044x over previous
//
#include <hip/hip_runtime.h>
#include <hip/hip_bf16.h>

typedef __hip_bfloat16 bf16;
typedef short s16x8 __attribute__((ext_vector_type(8)));
typedef float f32x4 __attribute__((ext_vector_type(4)));
typedef int   i32x4 __attribute__((ext_vector_type(4)));

// B=4 N=2048 E=512 H=8 K=128 D=192, D1=1536, tokens=8192, FFT length 8192

static __device__ __forceinline__ float silu_f(float v){
  return v / (1.f + __expf(-v));
}

// async global->LDS, 16B per lane; dest must be wave-uniform base + lane*16 (ours is)
#define GLDS16(g, l) __builtin_amdgcn_global_load_lds( \
    (const __attribute__((address_space(1))) void*)(g), \
    (__attribute__((address_space(3))) void*)(l), 16, 0, 0)

// ---------------- fused prep: all dtype converts/splits in one launch (r15, kept) ----------------
__global__ void prep_kernel(const float* __restrict__ x,  const float* __restrict__ Wu,
                            const float* __restrict__ Wv, const float* __restrict__ Wo,
                            const float* __restrict__ coef, const float* __restrict__ vander,
                            bf16* __restrict__ xb, bf16* __restrict__ wuv_hi, bf16* __restrict__ wuv_lo,
                            bf16* __restrict__ wo_b, bf16* __restrict__ ct_hi, bf16* __restrict__ ct_lo,
                            bf16* __restrict__ vb_hi, bf16* __restrict__ vb_lo){
  long i = (long)blockIdx.x * 256 + threadIdx.x;
  if (i < 4194304){ xb[i] = __float2bfloat16(x[i]); return; }
  i -= 4194304;
  if (i < 786432){
    float v = Wu[i]; bf16 h = __float2bfloat16(v);
    wuv_hi[i] = h; wuv_lo[i] = __float2bfloat16(v - __bfloat162float(h)); return;
  }
  i -= 786432;
  if (i < 786432){
    float v = Wv[i]; bf16 h = __float2bfloat16(v);
    wuv_hi[786432 + i] = h; wuv_lo[786432 + i] = __float2bfloat16(v - __bfloat162float(h)); return;
  }
  i -= 786432;
  if (i < 786432){ wo_b[i] = __float2bfloat16(Wo[i]); return; }
  i -= 786432;
  if (i < 196608){
    int hd = (int)(i >> 7), k = (int)(i & 127);
    int h = hd / 192, dd = hd - h * 192;
    float v = coef[(h * 128 + k) * 192 + dd];
    bf16 hb = __float2bfloat16(v);
    ct_hi[i] = hb; ct_lo[i] = __float2bfloat16(v - __bfloat162float(hb)); return;
  }
  i -= 196608;
  if (i < 524288){
    float v = (i >> 7) < 4095 ? vander[i] : 0.f;
    bf16 hb = __float2bfloat16(v);
    vb_hi[i] = hb; vb_lo[i] = __float2bfloat16(v - __bfloat162float(hb));
  }
}

// ---------------- GEMM: merged split-precision (r14 WIN) + optional XCD swizzle ----------------
__global__ __launch_bounds__(256)
void gemm_bf16(const bf16* __restrict__ A, const bf16* __restrict__ Alo,
               const bf16* __restrict__ Bt, const bf16* __restrict__ Btlo,
               int K, int N, int useAlo, int useBlo, int mode, int swizzle,
               const float* __restrict__ bias0, const float* __restrict__ bias1,
               void* __restrict__ out0, void* __restrict__ out1)
{
  __shared__ bf16 As [128 * 32];
  __shared__ bf16 Als[128 * 32];
  __shared__ bf16 Bs [128 * 32];
  __shared__ bf16 Bls[128 * 32];
  const int tid  = threadIdx.x;
  const int lane = tid & 63;
  const int wave = tid >> 6;
  const int wr = wave >> 1, wc = wave & 1;

  int bx = blockIdx.x, by = blockIdx.y;
  if (swizzle){
    // bijective XCD-chunked remap (nwg % 8 == 0 for all swizzled launches)
    const int nwg = gridDim.x * gridDim.y;
    const int id  = by * gridDim.x + bx;
    const int id2 = (id & 7) * (nwg >> 3) + (id >> 3);
    bx = id2 % gridDim.x; by = id2 / gridDim.x;
  }
  const int bm = by * 128;
  const int bn = bx * 128;

  const int c0i = tid, c1i = tid + 256;
  const int rA0 = c0i >> 2, cA0 = (c0i & 3) << 3;
  const int rA1 = c1i >> 2, cA1 = (c1i & 3) << 3;

  const bf16* Ab  = A  + (size_t)bm * K;
  const bf16* Alb = useAlo ? (Alo  + (size_t)bm * K) : nullptr;
  const bf16* Bb  = Bt + (size_t)bn * K;
  const bf16* Blb = useBlo ? (Btlo + (size_t)bn * K) : nullptr;

  f32x4 acc[4][4];
#pragma unroll
  for (int i = 0; i < 4; i++)
#pragma unroll
    for (int j = 0; j < 4; j++) acc[i][j] = (f32x4){0.f, 0.f, 0.f, 0.f};

  const int laneRow = lane & 15;
  const int laneK   = (lane >> 4) << 3;

  for (int k0 = 0; k0 < K; k0 += 32){
    __syncthreads();                   // prior iteration's LDS reads complete
    GLDS16(Ab + (size_t)rA0 * K + k0 + cA0, As + c0i * 8);
    GLDS16(Ab + (size_t)rA1 * K + k0 + cA1, As + c1i * 8);
    GLDS16(Bb + (size_t)rA0 * K + k0 + cA0, Bs + c0i * 8);
    GLDS16(Bb + (size_t)rA1 * K + k0 + cA1, Bs + c1i * 8);
    if (useBlo){
      GLDS16(Blb + (size_t)rA0 * K + k0 + cA0, Bls + c0i * 8);
      GLDS16(Blb + (size_t)rA1 * K + k0 + cA1, Bls + c1i * 8);
    }
    if (useAlo){
      GLDS16(Alb + (size_t)rA0 * K + k0 + cA0, Als + c0i * 8);
      GLDS16(Alb + (size_t)rA1 * K + k0 + cA1, Als + c1i * 8);
    }
    __syncthreads();                   // compiler drains vmcnt(0) before barrier
    s16x8 af[4], bv[4];
#pragma unroll
    for (int mi = 0; mi < 4; mi++)
      af[mi] = *(const s16x8*)(As + (wr * 64 + mi * 16 + laneRow) * 32 + laneK);
#pragma unroll
    for (int ni = 0; ni < 4; ni++)
      bv[ni] = *(const s16x8*)(Bs + (wc * 64 + ni * 16 + laneRow) * 32 + laneK);
#pragma unroll
    for (int mi = 0; mi < 4; mi++)
#pragma unroll
      for (int ni = 0; ni < 4; ni++)
        acc[mi][ni] = __builtin_amdgcn_mfma_f32_16x16x32_bf16(af[mi], bv[ni], acc[mi][ni], 0, 0, 0);
    if (useBlo){
      s16x8 bl[4];
#pragma unroll
      for (int ni = 0; ni < 4; ni++)
        bl[ni] = *(const s16x8*)(Bls + (wc * 64 + ni * 16 + laneRow) * 32 + laneK);
#pragma unroll
      for (int mi = 0; mi < 4; mi++)
#pragma unroll
        for (int ni = 0; ni < 4; ni++)
          acc[mi][ni] = __builtin_amdgcn_mfma_f32_16x16x32_bf16(af[mi], bl[ni], acc[mi][ni], 0, 0, 0);
    }
    if (useAlo){
      s16x8 al[4];
#pragma unroll
      for (int mi = 0; mi < 4; mi++)
        al[mi] = *(const s16x8*)(Als + (wr * 64 + mi * 16 + laneRow) * 32 + laneK);
#pragma unroll
      for (int mi = 0; mi < 4; mi++)
#pragma unroll
        for (int ni = 0; ni < 4; ni++)
          acc[mi][ni] = __builtin_amdgcn_mfma_f32_16x16x32_bf16(al[mi], bv[ni], acc[mi][ni], 0, 0, 0);
    }
  }

  const int rowOff = (lane >> 4) << 2;   // C/D: col = lane&15, row = (lane>>4)*4 + reg
#pragma unroll
  for (int mi = 0; mi < 4; mi++){
    const int rowb = bm + wr * 64 + mi * 16 + rowOff;
#pragma unroll
    for (int ni = 0; ni < 4; ni++){
      const int col = bn + wc * 64 + ni * 16 + laneRow;
#pragma unroll
      for (int r = 0; r < 4; r++){
        const int row = rowb + r;
        float val = acc[mi][ni][r];
        if (mode == 0){
          float bsv = (col < 1536) ? bias0[col] : bias1[col - 1536];
          val = silu_f(val + bsv);
          if (col < 1536) ((bf16*)out0)[(size_t)row * 1536 + col] = __float2bfloat16(val);
          else            ((bf16*)out1)[(size_t)row * 1536 + (col - 1536)] = __float2bfloat16(val);
        } else if (mode == 1){
          ((float*)out0)[(size_t)row * N + col] = val;
        } else {
          ((float*)out0)[(size_t)row * N + col] = val + bias0[col];
        }
      }
    }
  }
}

// ---------------- transpose / gate (unchanged) ----------------
__global__ void transpose_v_kernel(const bf16* __restrict__ v_nat, bf16* __restrict__ v_t){
  __shared__ bf16 tile[32][33];
  const int tx = threadIdx.x & 31, ty = threadIdx.x >> 5;
  const int c0 = blockIdx.x * 32;
  const int r0 = blockIdx.y * 32;
  const int b  = r0 >> 11;
  const int i0 = r0 & 2047;
#pragma unroll
  for (int yy = ty; yy < 32; yy += 8)
    tile[yy][tx] = v_nat[(size_t)(r0 + yy) * 1536 + c0 + tx];
  __syncthreads();
#pragma unroll
  for (int yy = ty; yy < 32; yy += 8)
    v_t[((size_t)b * 1536 + c0 + yy) * 2048 + i0 + tx] = tile[tx][yy];
}

__global__ void gate_kernel(const bf16* __restrict__ u_bf, const bf16* __restrict__ conv_t,
                            bf16* __restrict__ gateA){
  __shared__ bf16 tile[32][33];
  const int tx = threadIdx.x & 31, ty = threadIdx.x >> 5;
  const int c0 = blockIdx.x * 32;
  const int r0 = blockIdx.y * 32;
  const int b  = r0 >> 11;
  const int i0 = r0 & 2047;
#pragma unroll
  for (int yy = ty; yy < 32; yy += 8)
    tile[yy][tx] = conv_t[((size_t)b * 1536 + c0 + yy) * 2048 + i0 + tx];
  __syncthreads();
#pragma unroll
  for (int yy = ty; yy < 32; yy += 8){
    const size_t idx = (size_t)(r0 + yy) * 1536 + c0 + tx;
    float g = __bfloat162float(u_bf[idx]) * __bfloat162float(tile[tx][yy]);
    gateA[idx] = __float2bfloat16(g);
  }
}

// ---------------- FFT conv: r14-EXACT (verified local optimum, 164 us) ----------------
// PINNED: r12 (global tspec), r13 (split filter kernel), r15 (half2 LDS) all
// regressed — any added live state in this kernel trips spill at the 128-VGPR
// plateau that outweighs the occupancy/LDS gains. Do not modify without a
// structural redesign (e.g. 1024-thread / 8-elem-per-thread decomposition).

#define R2C 0.70710678118654752f

__device__ __forceinline__ int phys(int i){ return i + (i >> 3); }

#define SINCOS_REV(rev, sn_, cs_) { const float _rv = (rev); \
  sn_ = __builtin_amdgcn_sinf(_rv); cs_ = __builtin_amdgcn_cosf(_rv); }

#define BFF(xr,xi,yr,yi,tr_,ti_) { float sr_=(xr)-(yr), si_=(xi)-(yi); (xr)+=(yr); (xi)+=(yi); (yr)=sr_*(tr_)-si_*(ti_); (yi)=sr_*(ti_)+si_*(tr_); }
#define BFI(xr,xi,yr,yi,tr_,ti_) { float pr_=(yr)*(tr_)-(yi)*(ti_), pi_=(yr)*(ti_)+(yi)*(tr_); (yr)=(xr)-pr_; (yi)=(xi)-pi_; (xr)+=pr_; (xi)+=pi_; }

__device__ __forceinline__ void fwd_reg(float* r, float* m, int t){
  float sn, cs;
#pragma unroll
  for (int a = 0; a < 8; a++){
    SINCOS_REV(-(float)(t + 512*a) * (1.f/8192.f), sn, cs);
    BFF(r[a],m[a], r[a+8],m[a+8], cs, sn);
  }
#pragma unroll
  for (int a = 0; a < 4; a++){
    SINCOS_REV(-(float)(t + 512*a) * (1.f/4096.f), sn, cs);
    BFF(r[a],m[a], r[a+4],m[a+4], cs, sn);
    BFF(r[a+8],m[a+8], r[a+12],m[a+12], cs, sn);
  }
#pragma unroll
  for (int a = 0; a < 2; a++){
    SINCOS_REV(-(float)(t + 512*a) * (1.f/2048.f), sn, cs);
    BFF(r[a],m[a], r[a+2],m[a+2], cs, sn);
    BFF(r[a+4],m[a+4], r[a+6],m[a+6], cs, sn);
    BFF(r[a+8],m[a+8], r[a+10],m[a+10], cs, sn);
    BFF(r[a+12],m[a+12], r[a+14],m[a+14], cs, sn);
  }
  SINCOS_REV(-(float)t * (1.f/1024.f), sn, cs);
#pragma unroll
  for (int e = 0; e < 8; e++){
    BFF(r[2*e],m[2*e], r[2*e+1],m[2*e+1], cs, sn);
  }
}

__device__ __forceinline__ void inv_reg(float* r, float* m, int t){
  float sn, cs;
  SINCOS_REV((float)t * (1.f/1024.f), sn, cs);
#pragma unroll
  for (int e = 0; e < 8; e++){
    BFI(r[2*e],m[2*e], r[2*e+1],m[2*e+1], cs, sn);
  }
#pragma unroll
  for (int a = 0; a < 2; a++){
    SINCOS_REV((float)(t + 512*a) * (1.f/2048.f), sn, cs);
    BFI(r[a],m[a], r[a+2],m[a+2], cs, sn);
    BFI(r[a+4],m[a+4], r[a+6],m[a+6], cs, sn);
    BFI(r[a+8],m[a+8], r[a+10],m[a+10], cs, sn);
    BFI(r[a+12],m[a+12], r[a+14],m[a+14], cs, sn);
  }
#pragma unroll
  for (int a = 0; a < 4; a++){
    SINCOS_REV((float)(t + 512*a) * (1.f/4096.f), sn, cs);
    BFI(r[a],m[a], r[a+4],m[a+4], cs, sn);
    BFI(r[a+8],m[a+8], r[a+12],m[a+12], cs, sn);
  }
#pragma unroll
  for (int a = 0; a < 8; a++){
    SINCOS_REV((float)(t + 512*a) * (1.f/8192.f), sn, cs);
    BFI(r[a],m[a], r[a+8],m[a+8], cs, sn);
  }
}

__device__ __forceinline__ void lds_stage_fwd(float* reS, float* imS, int t, int stride){
  const int pos = (stride == 64) ? (t & 63) : (t & 7);
  float ui, ur;
  SINCOS_REV(-(float)pos / (float)(stride * 8), ui, ur);
  const float u2r = ur*ur - ui*ui, u2i = 2.f*ur*ui;
  const float u4r = u2r*u2r - u2i*u2i, u4i = 2.f*u2r*u2i;
  const float t1r[4] = { ur, R2C*(ur+ui), ui, R2C*(ui-ur) };
  const float t1i[4] = { ui, R2C*(ui-ur), -ur, -R2C*(ur+ui) };
  const float t2r[2] = { u2r, u2i };
  const float t2i[2] = { u2i, -u2r };
#pragma unroll
  for (int rep = 0; rep < 2; rep++){
    const int tau = t + rep*512;
    const int base = (stride == 64) ? (((tau >> 6) << 9) + (tau & 63))
                                    : (((tau >> 3) << 6) + (tau & 7));
    float zr[8], zi[8];
#pragma unroll
    for (int q = 0; q < 8; q++){ int ix = phys(base + stride*q); zr[q] = reS[ix]; zi[q] = imS[ix]; }
#pragma unroll
    for (int q = 0; q < 4; q++){ BFF(zr[q],zi[q], zr[q+4],zi[q+4], t1r[q], t1i[q]); }
    BFF(zr[0],zi[0], zr[2],zi[2], t2r[0], t2i[0]);
    BFF(zr[1],zi[1], zr[3],zi[3], t2r[1], t2i[1]);
    BFF(zr[4],zi[4], zr[6],zi[6], t2r[0], t2i[0]);
    BFF(zr[5],zi[5], zr[7],zi[7], t2r[1], t2i[1]);
    BFF(zr[0],zi[0], zr[1],zi[1], u4r, u4i);
    BFF(zr[2],zi[2], zr[3],zi[3], u4r, u4i);
    BFF(zr[4],zi[4], zr[5],zi[5], u4r, u4i);
    BFF(zr[6],zi[6], zr[7],zi[7], u4r, u4i);
#pragma unroll
    for (int q = 0; q < 8; q++){ int ix = phys(base + stride*q); reS[ix] = zr[q]; imS[ix] = zi[q]; }
  }
}

__device__ __forceinline__ void lds_stage_inv(float* reS, float* imS, int t, int stride){
  const int pos = (stride == 64) ? (t & 63) : (t & 7);
  float ui, ur;
  SINCOS_REV((float)pos / (float)(stride * 8), ui, ur);
  const float u2r = ur*ur - ui*ui, u2i = 2.f*ur*ui;
  const float u4r = u2r*u2r - u2i*u2i, u4i = 2.f*u2r*u2i;
  const float t1r[4] = { ur, R2C*(ur-ui), -ui, -R2C*(ur+ui) };
  const float t1i[4] = { ui, R2C*(ur+ui), ur, R2C*(ur-ui) };
  const float t2r[2] = { u2r, -u2i };
  const float t2i[2] = { u2i, u2r };
#pragma unroll
  for (int rep = 0; rep < 2; rep++){
    const int tau = t + rep*512;
    const int base = (stride == 64) ? (((tau >> 6) << 9) + (tau & 63))
                                    : (((tau >> 3) << 6) + (tau & 7));
    float zr[8], zi[8];
#pragma unroll
    for (int q = 0; q < 8; q++){ int ix = phys(base + stride*q); zr[q] = reS[ix]; zi[q] = imS[ix]; }
    BFI(zr[0],zi[0], zr[1],zi[1], u4r, u4i);
    BFI(zr[2],zi[2], zr[3],zi[3], u4r, u4i);
    BFI(zr[4],zi[4], zr[5],zi[5], u4r, u4i);
    BFI(zr[6],zi[6], zr[7],zi[7], u4r, u4i);
    BFI(zr[0],zi[0], zr[2],zi[2], t2r[0], t2i[0]);
    BFI(zr[1],zi[1], zr[3],zi[3], t2r[1], t2i[1]);
    BFI(zr[4],zi[4], zr[6],zi[6], t2r[0], t2i[0]);
    BFI(zr[5],zi[5], zr[7],zi[7], t2r[1], t2i[1]);
#pragma unroll
    for (int q = 0; q < 4; q++){ BFI(zr[q],zi[q], zr[q+4],zi[q+4], t1r[q], t1i[q]); }
#pragma unroll
    for (int q = 0; q < 8; q++){ int ix = phys(base + stride*q); reS[ix] = zr[q]; imS[ix] = zi[q]; }
  }
}

__device__ __forceinline__ void octet_fwd_c(float* zr, float* zi){
  BFF(zr[0],zi[0], zr[4],zi[4], 1.f, 0.f);
  BFF(zr[1],zi[1], zr[5],zi[5], R2C, -R2C);
  BFF(zr[2],zi[2], zr[6],zi[6], 0.f, -1.f);
  BFF(zr[3],zi[3], zr[7],zi[7], -R2C, -R2C);
  BFF(zr[0],zi[0], zr[2],zi[2], 1.f, 0.f);
  BFF(zr[1],zi[1], zr[3],zi[3], 0.f, -1.f);
  BFF(zr[4],zi[4], zr[6],zi[6], 1.f, 0.f);
  BFF(zr[5],zi[5], zr[7],zi[7], 0.f, -1.f);
  BFF(zr[0],zi[0], zr[1],zi[1], 1.f, 0.f);
  BFF(zr[2],zi[2], zr[3],zi[3], 1.f, 0.f);
  BFF(zr[4],zi[4], zr[5],zi[5], 1.f, 0.f);
  BFF(zr[6],zi[6], zr[7],zi[7], 1.f, 0.f);
}

__device__ __forceinline__ void octet_inv_c(float* zr, float* zi){
  BFI(zr[0],zi[0], zr[1],zi[1], 1.f, 0.f);
  BFI(zr[2],zi[2], zr[3],zi[3], 1.f, 0.f);
  BFI(zr[4],zi[4], zr[5],zi[5], 1.f, 0.f);
  BFI(zr[6],zi[6], zr[7],zi[7], 1.f, 0.f);
  BFI(zr[0],zi[0], zr[2],zi[2], 1.f, 0.f);
  BFI(zr[1],zi[1], zr[3],zi[3], 0.f, 1.f);
  BFI(zr[4],zi[4], zr[6],zi[6], 1.f, 0.f);
  BFI(zr[5],zi[5], zr[7],zi[7], 0.f, 1.f);
  BFI(zr[0],zi[0], zr[4],zi[4], 1.f, 0.f);
  BFI(zr[1],zi[1], zr[5],zi[5], R2C, R2C);
  BFI(zr[2],zi[2], zr[6],zi[6], 0.f, 1.f);
  BFI(zr[3],zi[3], zr[7],zi[7], -R2C, R2C);
}

__global__ __launch_bounds__(512, 1)
void conv_fft_kernel(const float* __restrict__ t_time, const bf16* __restrict__ v_t,
                     bf16* __restrict__ conv_t){
  __shared__ float reS[9216];   // phys(8191) = 9214
  __shared__ float imS[9216];
  __shared__ float Tsp[32 * 516];  // thread-private cols, stride 516 -> conflict-free
  const int t  = threadIdx.x;
  const int hd = blockIdx.x;
  float r[16], m[16];

  const float* trow = t_time + (size_t)hd * 4096;
#pragma unroll
  for (int a = 0; a < 16; a++){
    r[a] = (a < 8) ? trow[t + 512*a] : 0.f;
    m[a] = 0.f;
  }
  fwd_reg(r, m, t);
#pragma unroll
  for (int a = 0; a < 16; a++){ int ix = phys(t + 512*a); reS[ix] = r[a]; imS[ix] = m[a]; }
  __syncthreads();
  lds_stage_fwd(reS, imS, t, 64);
  __syncthreads();
  lds_stage_fwd(reS, imS, t, 8);
  __syncthreads();
#pragma unroll
  for (int o = 0; o < 2; o++){
    const int b8 = (t + 512*o) * 8;
    float zr[8], zi[8];
#pragma unroll
    for (int e = 0; e < 8; e++){ int ix = phys(b8 + e); zr[e] = reS[ix]; zi[e] = imS[ix]; }
    octet_fwd_c(zr, zi);
#pragma unroll
    for (int e = 0; e < 8; e++){
      Tsp[(2*(8*o+e)    ) * 516 + t] = zr[e];
      Tsp[(2*(8*o+e) + 1) * 516 + t] = zi[e];
    }
  }

  for (int pair = 0; pair < 2; pair++){
    const bf16* v0 = v_t + ((size_t)(2*pair)     * 1536 + hd) * 2048;
    const bf16* v1 = v_t + ((size_t)(2*pair + 1) * 1536 + hd) * 2048;
#pragma unroll
    for (int a = 0; a < 16; a++){
      if (a < 4){ int idx = t + 512*a; r[a] = __bfloat162float(v0[idx]); m[a] = __bfloat162float(v1[idx]); }
      else      { r[a] = 0.f; m[a] = 0.f; }
    }
    fwd_reg(r, m, t);
    __syncthreads();
#pragma unroll
    for (int a = 0; a < 16; a++){ int ix = phys(t + 512*a); reS[ix] = r[a]; imS[ix] = m[a]; }
    __syncthreads();
    lds_stage_fwd(reS, imS, t, 64);
    __syncthreads();
    lds_stage_fwd(reS, imS, t, 8);
    __syncthreads();
#pragma unroll
    for (int o = 0; o < 2; o++){
      const int b8 = (t + 512*o) * 8;
      float zr[8], zi[8];
#pragma unroll
      for (int e = 0; e < 8; e++){ int ix = phys(b8 + e); zr[e] = reS[ix]; zi[e] = imS[ix]; }
      octet_fwd_c(zr, zi);
#pragma unroll
      for (int e = 0; e < 8; e++){
        const float ar = zr[e], ai = zi[e];
        const float br = Tsp[(2*(8*o+e)    ) * 516 + t];
        const float bi = Tsp[(2*(8*o+e) + 1) * 516 + t];
        zr[e] = ar*br - ai*bi;
        zi[e] = ar*bi + ai*br;
      }
      octet_inv_c(zr, zi);
#pragma unroll
      for (int e = 0; e < 8; e++){ int ix = phys(b8 + e); reS[ix] = zr[e]; imS[ix] = zi[e]; }
    }
    __syncthreads();
    lds_stage_inv(reS, imS, t, 8);
    __syncthreads();
    lds_stage_inv(reS, imS, t, 64);
    __syncthreads();
#pragma unroll
    for (int a = 0; a < 16; a++){ int ix = phys(t + 512*a); r[a] = reS[ix]; m[a] = imS[ix]; }
    inv_reg(r, m, t);
    // window tau = 2047..4094 -> exact linear conv outputs 0..2047 (no wrap at L=8192)
    bf16* c0 = conv_t + ((size_t)(2*pair)     * 1536 + hd) * 2048;
    bf16* c1 = conv_t + ((size_t)(2*pair + 1) * 1536 + hd) * 2048;
    const float s = 1.f / 8192.f;
#pragma unroll
    for (int a = 0; a < 16; a++){
      const int j = t + 512*a - 2047;
      if (j >= 0 && j < 2048){
        c0[j] = __float2bfloat16(r[a] * s);
        c1[j] = __float2bfloat16(m[a] * s);
      }
    }
  }
}

extern "C" void kernel_launch(void* const* d_in, const int* in_sizes, int n_in,
                              void* d_out, int out_size, void* d_ws, size_t ws_size,
                              hipStream_t stream)
{
  (void)in_sizes; (void)n_in; (void)out_size; (void)ws_size;
  const float* x      = (const float*)d_in[0];
  const float* vander = (const float*)d_in[1];
  // d_in[2] = index (Toeplitz gather indices) — unused
  const float* coef   = (const float*)d_in[3];
  const float* Wu     = (const float*)d_in[4];
  const float* bu     = (const float*)d_in[5];
  const float* Wv     = (const float*)d_in[6];
  const float* bv     = (const float*)d_in[7];
  const float* Wo     = (const float*)d_in[8];
  const float* bo     = (const float*)d_in[9];

  char* ws = (char*)d_ws;
  size_t off = 0;
  auto alloc = [&](size_t bytes) -> void* { void* p = ws + off; off += bytes; return p; };

  bf16*  xb     = (bf16*) alloc((size_t)8192 * 512 * 2);    // x bf16
  bf16*  wuv_hi = (bf16*) alloc((size_t)3072 * 512 * 2);
  bf16*  wuv_lo = (bf16*) alloc((size_t)3072 * 512 * 2);
  bf16*  wo_b   = (bf16*) alloc((size_t)512 * 1536 * 2);
  bf16*  ct_hi  = (bf16*) alloc((size_t)1536 * 128 * 2);
  bf16*  ct_lo  = (bf16*) alloc((size_t)1536 * 128 * 2);
  bf16*  vb_hi  = (bf16*) alloc((size_t)4096 * 128 * 2);
  bf16*  vb_lo  = (bf16*) alloc((size_t)4096 * 128 * 2);
  bf16*  u_bf   = (bf16*) alloc((size_t)8192 * 1536 * 2);
  bf16*  v_bf   = (bf16*) alloc((size_t)8192 * 1536 * 2);   // (token, hd); reused as conv_t
  bf16*  v_t    = (bf16*) alloc((size_t)8192 * 1536 * 2);   // (b, hd, i)
  float* t_time = (float*)alloc((size_t)1536 * 4096 * 4);   // reused as gateA

  bf16* conv_t = v_bf;            // v_bf dead after transpose
  bf16* gateA  = (bf16*)t_time;   // t_time dead after conv kernel

  // all converts in one launch (7,274,496 items)
  prep_kernel<<<28416, 256, 0, stream>>>(x, Wu, Wv, Wo, coef, vander,
                                         xb, wuv_hi, wuv_lo, wo_b, ct_hi, ct_lo, vb_hi, vb_lo);

  // G1 (merged bf16x2, XCD-chunked swizzle): [u|v] = silu(x @ [Wu;Wv]^T + b)
  gemm_bf16<<<dim3(24, 64), 256, 0, stream>>>(xb, nullptr, wuv_hi, wuv_lo,
                                              512, 3072, 0, 1, 0, 1, bu, bv, u_bf, v_bf);
  transpose_v_kernel<<<dim3(48, 256), 256, 0, stream>>>(v_bf, v_t);
  // G2 (merged bf16x3): t = ct_hi*vb_hi + ct_hi*vb_lo + ct_lo*vb_hi
  gemm_bf16<<<dim3(32, 12), 256, 0, stream>>>(ct_hi, ct_lo, vb_hi, vb_lo,
                                              128, 4096, 1, 1, 1, 0, nullptr, nullptr, t_time, nullptr);
  // FFT convolution per hd channel (r14 config, PINNED)
  conv_fft_kernel<<<1536, 512, 0, stream>>>(t_time, v_t, conv_t);
  // gate: A = u * conv
  gate_kernel<<<dim3(48, 256), 256, 0, stream>>>(u_bf, conv_t, gateA);
  // G3: out = A @ Wo^T + bo  (8192 x 512, K=1536), fp32 store to d_out
  gemm_bf16<<<dim3(4, 64), 256, 0, stream>>>(gateA, gateA, wo_b, wo_b,
                                             1536, 512, 0, 0, 2, 0, bo, nullptr, d_out, nullptr);
}

// Round 18
// 321.721 us; speedup vs baseline: 1.2677x; 1.0526x over previous
//
#include <hip/hip_runtime.h>
#include <hip/hip_bf16.h>

typedef __hip_bfloat16 bf16;
typedef short s16x8 __attribute__((ext_vector_type(8)));
typedef short s16x4 __attribute__((ext_vector_type(4)));
typedef float f32x4 __attribute__((ext_vector_type(4)));
typedef int   i32x4 __attribute__((ext_vector_type(4)));

// B=4 N=2048 E=512 H=8 K=128 D=192, D1=1536, tokens=8192, FFT length 8192

static __device__ __forceinline__ float silu_f(float v){
  return v / (1.f + __expf(-v));
}

static __device__ __forceinline__ short bf16bits(float v){
  bf16 h = __float2bfloat16(v);
  return *(short*)&h;
}

static __device__ __forceinline__ float bits2f(short s){
  bf16 h = *(bf16*)&s;
  return __bfloat162float(h);
}

// async global->LDS, 16B per lane; dest must be wave-uniform base + lane*16 (ours is)
#define GLDS16(g, l) __builtin_amdgcn_global_load_lds( \
    (const __attribute__((address_space(1))) void*)(g), \
    (__attribute__((address_space(3))) void*)(l), 16, 0, 0)

// ---------------- fused prep, vectorized (float4 in, short4 out for dense parts) ----------------
__global__ void prep_kernel(const float* __restrict__ x,  const float* __restrict__ Wu,
                            const float* __restrict__ Wv, const float* __restrict__ Wo,
                            const float* __restrict__ coef, const float* __restrict__ vander,
                            bf16* __restrict__ xb, bf16* __restrict__ wuv_hi, bf16* __restrict__ wuv_lo,
                            bf16* __restrict__ wo_b, bf16* __restrict__ ct_hi, bf16* __restrict__ ct_lo,
                            bf16* __restrict__ vb_hi, bf16* __restrict__ vb_lo){
  long i = (long)blockIdx.x * 256 + threadIdx.x;
  // x: 4194304 elems as 1048576 float4
  if (i < 1048576){
    f32x4 v = *(const f32x4*)(x + 4*i);
    s16x4 o;
#pragma unroll
    for (int k = 0; k < 4; k++) o[k] = bf16bits(v[k]);
    *(s16x4*)(xb + 4*i) = o; return;
  }
  i -= 1048576;
  // Wu: 786432 as 196608 float4 (hi+lo)
  if (i < 196608){
    f32x4 v = *(const f32x4*)(Wu + 4*i);
    s16x4 hi, lo;
#pragma unroll
    for (int k = 0; k < 4; k++){
      bf16 h = __float2bfloat16(v[k]);
      hi[k] = *(short*)&h;
      lo[k] = bf16bits(v[k] - __bfloat162float(h));
    }
    *(s16x4*)(wuv_hi + 4*i) = hi; *(s16x4*)(wuv_lo + 4*i) = lo; return;
  }
  i -= 196608;
  // Wv: same, offset 786432
  if (i < 196608){
    f32x4 v = *(const f32x4*)(Wv + 4*i);
    s16x4 hi, lo;
#pragma unroll
    for (int k = 0; k < 4; k++){
      bf16 h = __float2bfloat16(v[k]);
      hi[k] = *(short*)&h;
      lo[k] = bf16bits(v[k] - __bfloat162float(h));
    }
    *(s16x4*)(wuv_hi + 786432 + 4*i) = hi; *(s16x4*)(wuv_lo + 786432 + 4*i) = lo; return;
  }
  i -= 196608;
  // Wo: 786432 as 196608 float4
  if (i < 196608){
    f32x4 v = *(const f32x4*)(Wo + 4*i);
    s16x4 o;
#pragma unroll
    for (int k = 0; k < 4; k++) o[k] = bf16bits(v[k]);
    *(s16x4*)(wo_b + 4*i) = o; return;
  }
  i -= 196608;
  // coef transpose: scalar (gather), 196608
  if (i < 196608){
    int hd = (int)(i >> 7), k = (int)(i & 127);
    int h = hd / 192, dd = hd - h * 192;
    float v = coef[(h * 128 + k) * 192 + dd];
    bf16 hb = __float2bfloat16(v);
    ct_hi[i] = hb; ct_lo[i] = __float2bfloat16(v - __bfloat162float(hb)); return;
  }
  i -= 196608;
  // vander pad: 524288 as 131072 float4 (rows 0..4094 dense; row 4095 zero)
  if (i < 131072){
    long e0 = 4*i;
    s16x4 hi, lo;
#pragma unroll
    for (int k = 0; k < 4; k++){
      long e = e0 + k;
      float v = (e >> 7) < 4095 ? vander[e] : 0.f;
      bf16 h = __float2bfloat16(v);
      hi[k] = *(short*)&h;
      lo[k] = bf16bits(v - __bfloat162float(h));
    }
    *(s16x4*)(vb_hi + e0) = hi; *(s16x4*)(vb_lo + e0) = lo;
  }
}

// ---------------- GEMM: merged split-precision (r14 WIN) + optional XCD swizzle ----------------
__global__ __launch_bounds__(256)
void gemm_bf16(const bf16* __restrict__ A, const bf16* __restrict__ Alo,
               const bf16* __restrict__ Bt, const bf16* __restrict__ Btlo,
               int K, int N, int useAlo, int useBlo, int mode, int swizzle,
               const float* __restrict__ bias0, const float* __restrict__ bias1,
               void* __restrict__ out0, void* __restrict__ out1)
{
  __shared__ bf16 As [128 * 32];
  __shared__ bf16 Als[128 * 32];
  __shared__ bf16 Bs [128 * 32];
  __shared__ bf16 Bls[128 * 32];
  const int tid  = threadIdx.x;
  const int lane = tid & 63;
  const int wave = tid >> 6;
  const int wr = wave >> 1, wc = wave & 1;

  int bx = blockIdx.x, by = blockIdx.y;
  if (swizzle){
    const int nwg = gridDim.x * gridDim.y;
    const int id  = by * gridDim.x + bx;
    const int id2 = (id & 7) * (nwg >> 3) + (id >> 3);
    bx = id2 % gridDim.x; by = id2 / gridDim.x;
  }
  const int bm = by * 128;
  const int bn = bx * 128;

  const int c0i = tid, c1i = tid + 256;
  const int rA0 = c0i >> 2, cA0 = (c0i & 3) << 3;
  const int rA1 = c1i >> 2, cA1 = (c1i & 3) << 3;

  const bf16* Ab  = A  + (size_t)bm * K;
  const bf16* Alb = useAlo ? (Alo  + (size_t)bm * K) : nullptr;
  const bf16* Bb  = Bt + (size_t)bn * K;
  const bf16* Blb = useBlo ? (Btlo + (size_t)bn * K) : nullptr;

  f32x4 acc[4][4];
#pragma unroll
  for (int i = 0; i < 4; i++)
#pragma unroll
    for (int j = 0; j < 4; j++) acc[i][j] = (f32x4){0.f, 0.f, 0.f, 0.f};

  const int laneRow = lane & 15;
  const int laneK   = (lane >> 4) << 3;

  for (int k0 = 0; k0 < K; k0 += 32){
    __syncthreads();
    GLDS16(Ab + (size_t)rA0 * K + k0 + cA0, As + c0i * 8);
    GLDS16(Ab + (size_t)rA1 * K + k0 + cA1, As + c1i * 8);
    GLDS16(Bb + (size_t)rA0 * K + k0 + cA0, Bs + c0i * 8);
    GLDS16(Bb + (size_t)rA1 * K + k0 + cA1, Bs + c1i * 8);
    if (useBlo){
      GLDS16(Blb + (size_t)rA0 * K + k0 + cA0, Bls + c0i * 8);
      GLDS16(Blb + (size_t)rA1 * K + k0 + cA1, Bls + c1i * 8);
    }
    if (useAlo){
      GLDS16(Alb + (size_t)rA0 * K + k0 + cA0, Als + c0i * 8);
      GLDS16(Alb + (size_t)rA1 * K + k0 + cA1, Als + c1i * 8);
    }
    __syncthreads();
    s16x8 af[4], bv[4];
#pragma unroll
    for (int mi = 0; mi < 4; mi++)
      af[mi] = *(const s16x8*)(As + (wr * 64 + mi * 16 + laneRow) * 32 + laneK);
#pragma unroll
    for (int ni = 0; ni < 4; ni++)
      bv[ni] = *(const s16x8*)(Bs + (wc * 64 + ni * 16 + laneRow) * 32 + laneK);
#pragma unroll
    for (int mi = 0; mi < 4; mi++)
#pragma unroll
      for (int ni = 0; ni < 4; ni++)
        acc[mi][ni] = __builtin_amdgcn_mfma_f32_16x16x32_bf16(af[mi], bv[ni], acc[mi][ni], 0, 0, 0);
    if (useBlo){
      s16x8 bl[4];
#pragma unroll
      for (int ni = 0; ni < 4; ni++)
        bl[ni] = *(const s16x8*)(Bls + (wc * 64 + ni * 16 + laneRow) * 32 + laneK);
#pragma unroll
      for (int mi = 0; mi < 4; mi++)
#pragma unroll
        for (int ni = 0; ni < 4; ni++)
          acc[mi][ni] = __builtin_amdgcn_mfma_f32_16x16x32_bf16(af[mi], bl[ni], acc[mi][ni], 0, 0, 0);
    }
    if (useAlo){
      s16x8 al[4];
#pragma unroll
      for (int mi = 0; mi < 4; mi++)
        al[mi] = *(const s16x8*)(Als + (wr * 64 + mi * 16 + laneRow) * 32 + laneK);
#pragma unroll
      for (int mi = 0; mi < 4; mi++)
#pragma unroll
        for (int ni = 0; ni < 4; ni++)
          acc[mi][ni] = __builtin_amdgcn_mfma_f32_16x16x32_bf16(al[mi], bv[ni], acc[mi][ni], 0, 0, 0);
    }
  }

  const int rowOff = (lane >> 4) << 2;
#pragma unroll
  for (int mi = 0; mi < 4; mi++){
    const int rowb = bm + wr * 64 + mi * 16 + rowOff;
#pragma unroll
    for (int ni = 0; ni < 4; ni++){
      const int col = bn + wc * 64 + ni * 16 + laneRow;
#pragma unroll
      for (int r = 0; r < 4; r++){
        const int row = rowb + r;
        float val = acc[mi][ni][r];
        if (mode == 0){
          float bsv = (col < 1536) ? bias0[col] : bias1[col - 1536];
          val = silu_f(val + bsv);
          if (col < 1536) ((bf16*)out0)[(size_t)row * 1536 + col] = __float2bfloat16(val);
          else            ((bf16*)out1)[(size_t)row * 1536 + (col - 1536)] = __float2bfloat16(val);
        } else if (mode == 1){
          ((float*)out0)[(size_t)row * N + col] = val;
        } else {
          ((float*)out0)[(size_t)row * N + col] = val + bias0[col];
        }
      }
    }
  }
}

// ---------------- transpose, vectorized: 64x64 tile, short8 global accesses ----------------
__global__ void transpose_v_kernel(const bf16* __restrict__ v_nat, bf16* __restrict__ v_t){
  __shared__ bf16 tile[64][72];          // +8 pad, rows 144B (16B-aligned)
  const int tx = threadIdx.x & 7;        // 8 threads x 8 elems = 64 cols
  const int ty = threadIdx.x >> 3;       // 32 rows per iter
  const int c0 = blockIdx.x * 64;        // hd   (1536/64 = 24)
  const int r0 = blockIdx.y * 64;        // token (8192/64 = 128), within one b (2048%64==0)
  const int b  = r0 >> 11;
  const int i0 = r0 & 2047;
#pragma unroll
  for (int it = 0; it < 2; it++){
    const int row = ty + it * 32;
    *(s16x8*)&tile[row][tx * 8] =
      *(const s16x8*)(v_nat + (size_t)(r0 + row) * 1536 + c0 + tx * 8);
  }
  __syncthreads();
#pragma unroll
  for (int it = 0; it < 2; it++){
    const int hd = ty + it * 32;
    s16x8 vv;
#pragma unroll
    for (int k = 0; k < 8; k++){
      bf16 tv = tile[tx * 8 + k][hd];
      vv[k] = *(short*)&tv;
    }
    *(s16x8*)(v_t + ((size_t)b * 1536 + c0 + hd) * 2048 + i0 + tx * 8) = vv;
  }
}

// ---------------- gate, vectorized: A = u * conv (conv (b,hd,i) -> (token,hd)) ----------------
__global__ void gate_kernel(const bf16* __restrict__ u_bf, const bf16* __restrict__ conv_t,
                            bf16* __restrict__ gateA){
  __shared__ bf16 tile[64][72];
  const int tx = threadIdx.x & 7;
  const int ty = threadIdx.x >> 3;
  const int c0 = blockIdx.x * 64;        // hd
  const int r0 = blockIdx.y * 64;        // token
  const int b  = r0 >> 11;
  const int i0 = r0 & 2047;
#pragma unroll
  for (int it = 0; it < 2; it++){
    const int hd = ty + it * 32;
    *(s16x8*)&tile[hd][tx * 8] =
      *(const s16x8*)(conv_t + ((size_t)b * 1536 + c0 + hd) * 2048 + i0 + tx * 8);
  }
  __syncthreads();
#pragma unroll
  for (int it = 0; it < 2; it++){
    const int row = ty + it * 32;        // token offset in tile
    s16x8 uu = *(const s16x8*)(u_bf + (size_t)(r0 + row) * 1536 + c0 + tx * 8);
    s16x8 oo;
#pragma unroll
    for (int k = 0; k < 8; k++){
      short us = uu[k];
      bf16 cb = tile[tx * 8 + k][row];
      float g = bits2f(us) * __bfloat162float(cb);
      oo[k] = bf16bits(g);
    }
    *(s16x8*)(gateA + (size_t)(r0 + row) * 1536 + c0 + tx * 8) = oo;
  }
}

// ---------------- FFT conv: r14-EXACT (verified local optimum, 164 us) — PINNED ----------------
// r12 (global tspec), r13 (split filter kernel), r15 (half2 LDS) all regressed:
// any added live state trips spill at the 128-VGPR plateau. Do not modify.

#define R2C 0.70710678118654752f

__device__ __forceinline__ int phys(int i){ return i + (i >> 3); }

#define SINCOS_REV(rev, sn_, cs_) { const float _rv = (rev); \
  sn_ = __builtin_amdgcn_sinf(_rv); cs_ = __builtin_amdgcn_cosf(_rv); }

#define BFF(xr,xi,yr,yi,tr_,ti_) { float sr_=(xr)-(yr), si_=(xi)-(yi); (xr)+=(yr); (xi)+=(yi); (yr)=sr_*(tr_)-si_*(ti_); (yi)=sr_*(ti_)+si_*(tr_); }
#define BFI(xr,xi,yr,yi,tr_,ti_) { float pr_=(yr)*(tr_)-(yi)*(ti_), pi_=(yr)*(ti_)+(yi)*(tr_); (yr)=(xr)-pr_; (yi)=(xi)-pi_; (xr)+=pr_; (xi)+=pi_; }

__device__ __forceinline__ void fwd_reg(float* r, float* m, int t){
  float sn, cs;
#pragma unroll
  for (int a = 0; a < 8; a++){
    SINCOS_REV(-(float)(t + 512*a) * (1.f/8192.f), sn, cs);
    BFF(r[a],m[a], r[a+8],m[a+8], cs, sn);
  }
#pragma unroll
  for (int a = 0; a < 4; a++){
    SINCOS_REV(-(float)(t + 512*a) * (1.f/4096.f), sn, cs);
    BFF(r[a],m[a], r[a+4],m[a+4], cs, sn);
    BFF(r[a+8],m[a+8], r[a+12],m[a+12], cs, sn);
  }
#pragma unroll
  for (int a = 0; a < 2; a++){
    SINCOS_REV(-(float)(t + 512*a) * (1.f/2048.f), sn, cs);
    BFF(r[a],m[a], r[a+2],m[a+2], cs, sn);
    BFF(r[a+4],m[a+4], r[a+6],m[a+6], cs, sn);
    BFF(r[a+8],m[a+8], r[a+10],m[a+10], cs, sn);
    BFF(r[a+12],m[a+12], r[a+14],m[a+14], cs, sn);
  }
  SINCOS_REV(-(float)t * (1.f/1024.f), sn, cs);
#pragma unroll
  for (int e = 0; e < 8; e++){
    BFF(r[2*e],m[2*e], r[2*e+1],m[2*e+1], cs, sn);
  }
}

__device__ __forceinline__ void inv_reg(float* r, float* m, int t){
  float sn, cs;
  SINCOS_REV((float)t * (1.f/1024.f), sn, cs);
#pragma unroll
  for (int e = 0; e < 8; e++){
    BFI(r[2*e],m[2*e], r[2*e+1],m[2*e+1], cs, sn);
  }
#pragma unroll
  for (int a = 0; a < 2; a++){
    SINCOS_REV((float)(t + 512*a) * (1.f/2048.f), sn, cs);
    BFI(r[a],m[a], r[a+2],m[a+2], cs, sn);
    BFI(r[a+4],m[a+4], r[a+6],m[a+6], cs, sn);
    BFI(r[a+8],m[a+8], r[a+10],m[a+10], cs, sn);
    BFI(r[a+12],m[a+12], r[a+14],m[a+14], cs, sn);
  }
#pragma unroll
  for (int a = 0; a < 4; a++){
    SINCOS_REV((float)(t + 512*a) * (1.f/4096.f), sn, cs);
    BFI(r[a],m[a], r[a+4],m[a+4], cs, sn);
    BFI(r[a+8],m[a+8], r[a+12],m[a+12], cs, sn);
  }
#pragma unroll
  for (int a = 0; a < 8; a++){
    SINCOS_REV((float)(t + 512*a) * (1.f/8192.f), sn, cs);
    BFI(r[a],m[a], r[a+8],m[a+8], cs, sn);
  }
}

__device__ __forceinline__ void lds_stage_fwd(float* reS, float* imS, int t, int stride){
  const int pos = (stride == 64) ? (t & 63) : (t & 7);
  float ui, ur;
  SINCOS_REV(-(float)pos / (float)(stride * 8), ui, ur);
  const float u2r = ur*ur - ui*ui, u2i = 2.f*ur*ui;
  const float u4r = u2r*u2r - u2i*u2i, u4i = 2.f*u2r*u2i;
  const float t1r[4] = { ur, R2C*(ur+ui), ui, R2C*(ui-ur) };
  const float t1i[4] = { ui, R2C*(ui-ur), -ur, -R2C*(ur+ui) };
  const float t2r[2] = { u2r, u2i };
  const float t2i[2] = { u2i, -u2r };
#pragma unroll
  for (int rep = 0; rep < 2; rep++){
    const int tau = t + rep*512;
    const int base = (stride == 64) ? (((tau >> 6) << 9) + (tau & 63))
                                    : (((tau >> 3) << 6) + (tau & 7));
    float zr[8], zi[8];
#pragma unroll
    for (int q = 0; q < 8; q++){ int ix = phys(base + stride*q); zr[q] = reS[ix]; zi[q] = imS[ix]; }
#pragma unroll
    for (int q = 0; q < 4; q++){ BFF(zr[q],zi[q], zr[q+4],zi[q+4], t1r[q], t1i[q]); }
    BFF(zr[0],zi[0], zr[2],zi[2], t2r[0], t2i[0]);
    BFF(zr[1],zi[1], zr[3],zi[3], t2r[1], t2i[1]);
    BFF(zr[4],zi[4], zr[6],zi[6], t2r[0], t2i[0]);
    BFF(zr[5],zi[5], zr[7],zi[7], t2r[1], t2i[1]);
    BFF(zr[0],zi[0], zr[1],zi[1], u4r, u4i);
    BFF(zr[2],zi[2], zr[3],zi[3], u4r, u4i);
    BFF(zr[4],zi[4], zr[5],zi[5], u4r, u4i);
    BFF(zr[6],zi[6], zr[7],zi[7], u4r, u4i);
#pragma unroll
    for (int q = 0; q < 8; q++){ int ix = phys(base + stride*q); reS[ix] = zr[q]; imS[ix] = zi[q]; }
  }
}

__device__ __forceinline__ void lds_stage_inv(float* reS, float* imS, int t, int stride){
  const int pos = (stride == 64) ? (t & 63) : (t & 7);
  float ui, ur;
  SINCOS_REV((float)pos / (float)(stride * 8), ui, ur);
  const float u2r = ur*ur - ui*ui, u2i = 2.f*ur*ui;
  const float u4r = u2r*u2r - u2i*u2i, u4i = 2.f*u2r*u2i;
  const float t1r[4] = { ur, R2C*(ur-ui), -ui, -R2C*(ur+ui) };
  const float t1i[4] = { ui, R2C*(ur+ui), ur, R2C*(ur-ui) };
  const float t2r[2] = { u2r, -u2i };
  const float t2i[2] = { u2i, u2r };
#pragma unroll
  for (int rep = 0; rep < 2; rep++){
    const int tau = t + rep*512;
    const int base = (stride == 64) ? (((tau >> 6) << 9) + (tau & 63))
                                    : (((tau >> 3) << 6) + (tau & 7));
    float zr[8], zi[8];
#pragma unroll
    for (int q = 0; q < 8; q++){ int ix = phys(base + stride*q); zr[q] = reS[ix]; zi[q] = imS[ix]; }
    BFI(zr[0],zi[0], zr[1],zi[1], u4r, u4i);
    BFI(zr[2],zi[2], zr[3],zi[3], u4r, u4i);
    BFI(zr[4],zi[4], zr[5],zi[5], u4r, u4i);
    BFI(zr[6],zi[6], zr[7],zi[7], u4r, u4i);
    BFI(zr[0],zi[0], zr[2],zi[2], t2r[0], t2i[0]);
    BFI(zr[1],zi[1], zr[3],zi[3], t2r[1], t2i[1]);
    BFI(zr[4],zi[4], zr[6],zi[6], t2r[0], t2i[0]);
    BFI(zr[5],zi[5], zr[7],zi[7], t2r[1], t2i[1]);
#pragma unroll
    for (int q = 0; q < 4; q++){ BFI(zr[q],zi[q], zr[q+4],zi[q+4], t1r[q], t1i[q]); }
#pragma unroll
    for (int q = 0; q < 8; q++){ int ix = phys(base + stride*q); reS[ix] = zr[q]; imS[ix] = zi[q]; }
  }
}

__device__ __forceinline__ void octet_fwd_c(float* zr, float* zi){
  BFF(zr[0],zi[0], zr[4],zi[4], 1.f, 0.f);
  BFF(zr[1],zi[1], zr[5],zi[5], R2C, -R2C);
  BFF(zr[2],zi[2], zr[6],zi[6], 0.f, -1.f);
  BFF(zr[3],zi[3], zr[7],zi[7], -R2C, -R2C);
  BFF(zr[0],zi[0], zr[2],zi[2], 1.f, 0.f);
  BFF(zr[1],zi[1], zr[3],zi[3], 0.f, -1.f);
  BFF(zr[4],zi[4], zr[6],zi[6], 1.f, 0.f);
  BFF(zr[5],zi[5], zr[7],zi[7], 0.f, -1.f);
  BFF(zr[0],zi[0], zr[1],zi[1], 1.f, 0.f);
  BFF(zr[2],zi[2], zr[3],zi[3], 1.f, 0.f);
  BFF(zr[4],zi[4], zr[5],zi[5], 1.f, 0.f);
  BFF(zr[6],zi[6], zr[7],zi[7], 1.f, 0.f);
}

__device__ __forceinline__ void octet_inv_c(float* zr, float* zi){
  BFI(zr[0],zi[0], zr[1],zi[1], 1.f, 0.f);
  BFI(zr[2],zi[2], zr[3],zi[3], 1.f, 0.f);
  BFI(zr[4],zi[4], zr[5],zi[5], 1.f, 0.f);
  BFI(zr[6],zi[6], zr[7],zi[7], 1.f, 0.f);
  BFI(zr[0],zi[0], zr[2],zi[2], 1.f, 0.f);
  BFI(zr[1],zi[1], zr[3],zi[3], 0.f, 1.f);
  BFI(zr[4],zi[4], zr[6],zi[6], 1.f, 0.f);
  BFI(zr[5],zi[5], zr[7],zi[7], 0.f, 1.f);
  BFI(zr[0],zi[0], zr[4],zi[4], 1.f, 0.f);
  BFI(zr[1],zi[1], zr[5],zi[5], R2C, R2C);
  BFI(zr[2],zi[2], zr[6],zi[6], 0.f, 1.f);
  BFI(zr[3],zi[3], zr[7],zi[7], -R2C, R2C);
}

__global__ __launch_bounds__(512, 1)
void conv_fft_kernel(const float* __restrict__ t_time, const bf16* __restrict__ v_t,
                     bf16* __restrict__ conv_t){
  __shared__ float reS[9216];   // phys(8191) = 9214
  __shared__ float imS[9216];
  __shared__ float Tsp[32 * 516];  // thread-private cols, stride 516 -> conflict-free
  const int t  = threadIdx.x;
  const int hd = blockIdx.x;
  float r[16], m[16];

  const float* trow = t_time + (size_t)hd * 4096;
#pragma unroll
  for (int a = 0; a < 16; a++){
    r[a] = (a < 8) ? trow[t + 512*a] : 0.f;
    m[a] = 0.f;
  }
  fwd_reg(r, m, t);
#pragma unroll
  for (int a = 0; a < 16; a++){ int ix = phys(t + 512*a); reS[ix] = r[a]; imS[ix] = m[a]; }
  __syncthreads();
  lds_stage_fwd(reS, imS, t, 64);
  __syncthreads();
  lds_stage_fwd(reS, imS, t, 8);
  __syncthreads();
#pragma unroll
  for (int o = 0; o < 2; o++){
    const int b8 = (t + 512*o) * 8;
    float zr[8], zi[8];
#pragma unroll
    for (int e = 0; e < 8; e++){ int ix = phys(b8 + e); zr[e] = reS[ix]; zi[e] = imS[ix]; }
    octet_fwd_c(zr, zi);
#pragma unroll
    for (int e = 0; e < 8; e++){
      Tsp[(2*(8*o+e)    ) * 516 + t] = zr[e];
      Tsp[(2*(8*o+e) + 1) * 516 + t] = zi[e];
    }
  }

  for (int pair = 0; pair < 2; pair++){
    const bf16* v0 = v_t + ((size_t)(2*pair)     * 1536 + hd) * 2048;
    const bf16* v1 = v_t + ((size_t)(2*pair + 1) * 1536 + hd) * 2048;
#pragma unroll
    for (int a = 0; a < 16; a++){
      if (a < 4){ int idx = t + 512*a; r[a] = __bfloat162float(v0[idx]); m[a] = __bfloat162float(v1[idx]); }
      else      { r[a] = 0.f; m[a] = 0.f; }
    }
    fwd_reg(r, m, t);
    __syncthreads();
#pragma unroll
    for (int a = 0; a < 16; a++){ int ix = phys(t + 512*a); reS[ix] = r[a]; imS[ix] = m[a]; }
    __syncthreads();
    lds_stage_fwd(reS, imS, t, 64);
    __syncthreads();
    lds_stage_fwd(reS, imS, t, 8);
    __syncthreads();
#pragma unroll
    for (int o = 0; o < 2; o++){
      const int b8 = (t + 512*o) * 8;
      float zr[8], zi[8];
#pragma unroll
      for (int e = 0; e < 8; e++){ int ix = phys(b8 + e); zr[e] = reS[ix]; zi[e] = imS[ix]; }
      octet_fwd_c(zr, zi);
#pragma unroll
      for (int e = 0; e < 8; e++){
        const float ar = zr[e], ai = zi[e];
        const float br = Tsp[(2*(8*o+e)    ) * 516 + t];
        const float bi = Tsp[(2*(8*o+e) + 1) * 516 + t];
        zr[e] = ar*br - ai*bi;
        zi[e] = ar*bi + ai*br;
      }
      octet_inv_c(zr, zi);
#pragma unroll
      for (int e = 0; e < 8; e++){ int ix = phys(b8 + e); reS[ix] = zr[e]; imS[ix] = zi[e]; }
    }
    __syncthreads();
    lds_stage_inv(reS, imS, t, 8);
    __syncthreads();
    lds_stage_inv(reS, imS, t, 64);
    __syncthreads();
#pragma unroll
    for (int a = 0; a < 16; a++){ int ix = phys(t + 512*a); r[a] = reS[ix]; m[a] = imS[ix]; }
    inv_reg(r, m, t);
    // window tau = 2047..4094 -> exact linear conv outputs 0..2047 (no wrap at L=8192)
    bf16* c0 = conv_t + ((size_t)(2*pair)     * 1536 + hd) * 2048;
    bf16* c1 = conv_t + ((size_t)(2*pair + 1) * 1536 + hd) * 2048;
    const float s = 1.f / 8192.f;
#pragma unroll
    for (int a = 0; a < 16; a++){
      const int j = t + 512*a - 2047;
      if (j >= 0 && j < 2048){
        c0[j] = __float2bfloat16(r[a] * s);
        c1[j] = __float2bfloat16(m[a] * s);
      }
    }
  }
}

extern "C" void kernel_launch(void* const* d_in, const int* in_sizes, int n_in,
                              void* d_out, int out_size, void* d_ws, size_t ws_size,
                              hipStream_t stream)
{
  (void)in_sizes; (void)n_in; (void)out_size; (void)ws_size;
  const float* x      = (const float*)d_in[0];
  const float* vander = (const float*)d_in[1];
  // d_in[2] = index (Toeplitz gather indices) — unused
  const float* coef   = (const float*)d_in[3];
  const float* Wu     = (const float*)d_in[4];
  const float* bu     = (const float*)d_in[5];
  const float* Wv     = (const float*)d_in[6];
  const float* bv     = (const float*)d_in[7];
  const float* Wo     = (const float*)d_in[8];
  const float* bo     = (const float*)d_in[9];

  char* ws = (char*)d_ws;
  size_t off = 0;
  auto alloc = [&](size_t bytes) -> void* { void* p = ws + off; off += bytes; return p; };

  bf16*  xb     = (bf16*) alloc((size_t)8192 * 512 * 2);    // x bf16
  bf16*  wuv_hi = (bf16*) alloc((size_t)3072 * 512 * 2);
  bf16*  wuv_lo = (bf16*) alloc((size_t)3072 * 512 * 2);
  bf16*  wo_b   = (bf16*) alloc((size_t)512 * 1536 * 2);
  bf16*  ct_hi  = (bf16*) alloc((size_t)1536 * 128 * 2);
  bf16*  ct_lo  = (bf16*) alloc((size_t)1536 * 128 * 2);
  bf16*  vb_hi  = (bf16*) alloc((size_t)4096 * 128 * 2);
  bf16*  vb_lo  = (bf16*) alloc((size_t)4096 * 128 * 2);
  bf16*  u_bf   = (bf16*) alloc((size_t)8192 * 1536 * 2);
  bf16*  v_bf   = (bf16*) alloc((size_t)8192 * 1536 * 2);   // (token, hd); reused as conv_t
  bf16*  v_t    = (bf16*) alloc((size_t)8192 * 1536 * 2);   // (b, hd, i)
  float* t_time = (float*)alloc((size_t)1536 * 4096 * 4);   // reused as gateA

  bf16* conv_t = v_bf;            // v_bf dead after transpose
  bf16* gateA  = (bf16*)t_time;   // t_time dead after conv kernel

  // prep: 2,359,296 threads (vectorized x/Wu/Wv/Wo/vander; scalar coef gather)
  prep_kernel<<<9216, 256, 0, stream>>>(x, Wu, Wv, Wo, coef, vander,
                                        xb, wuv_hi, wuv_lo, wo_b, ct_hi, ct_lo, vb_hi, vb_lo);

  // G1 (merged bf16x2, XCD-chunked swizzle): [u|v] = silu(x @ [Wu;Wv]^T + b)
  gemm_bf16<<<dim3(24, 64), 256, 0, stream>>>(xb, nullptr, wuv_hi, wuv_lo,
                                              512, 3072, 0, 1, 0, 1, bu, bv, u_bf, v_bf);
  transpose_v_kernel<<<dim3(24, 128), 256, 0, stream>>>(v_bf, v_t);
  // G2 (merged bf16x3): t = ct_hi*vb_hi + ct_hi*vb_lo + ct_lo*vb_hi
  gemm_bf16<<<dim3(32, 12), 256, 0, stream>>>(ct_hi, ct_lo, vb_hi, vb_lo,
                                              128, 4096, 1, 1, 1, 0, nullptr, nullptr, t_time, nullptr);
  // FFT convolution per hd channel (r14 config, PINNED)
  conv_fft_kernel<<<1536, 512, 0, stream>>>(t_time, v_t, conv_t);
  // gate: A = u * conv
  gate_kernel<<<dim3(24, 128), 256, 0, stream>>>(u_bf, conv_t, gateA);
  // G3: out = A @ Wo^T + bo  (8192 x 512, K=1536), fp32 store to d_out
  gemm_bf16<<<dim3(4, 64), 256, 0, stream>>>(gateA, gateA, wo_b, wo_b,
                                             1536, 512, 0, 0, 2, 0, bo, nullptr, d_out, nullptr);
}